// Round 24
// baseline (626.161 us; speedup 1.0000x reference)
//
#include <hip/hip_runtime.h>
#include <hip/hip_bf16.h>
#include <hip/hip_fp16.h>
#include <math.h>

constexpr int NE = 400000;
constexpr int NN = 40000;
constexpr int CD = 64;
constexpr int NGRAPH = 64;
constexpr int SCAN_BLOCKS = (NN + 255) / 256;   // 157
constexpr int EBLK = (NE + 255) / 256;          // 1563
constexpr int NBUCK = NN / 32;                  // 1250 buckets of 32 rows

typedef _Float16 f16x8 __attribute__((ext_vector_type(8)));
typedef float f32x4 __attribute__((ext_vector_type(4)));

// ---------------- fc1: x0 = relu(x @ fc1_w + b) ----------------
__global__ void k_fc1(const float* __restrict__ x,
                      const float* __restrict__ w,
                      const float* __restrict__ b,
                      float* __restrict__ out) {
    int i = blockIdx.x * 256 + threadIdx.x;
    if (i >= NN * CD) return;
    int n = i >> 6, c = i & 63;
    float acc = b[c];
    #pragma unroll
    for (int k = 0; k < 9; ++k)
        acc = fmaf(x[n * 9 + k], w[k * 64 + c], acc);
    out[i] = fmaxf(acc, 0.f);
}

// ---------------- edge counts, both sets ----------------
__global__ void k_count2(const int* __restrict__ ei1, const int* __restrict__ ei2,
                         int* __restrict__ cnt1, int* __restrict__ cnt2) {
    const int b = blockIdx.x;
    const bool s2 = (b >= EBLK);
    const int* ei = s2 ? ei2 : ei1;
    int* cnt = s2 ? cnt2 : cnt1;
    int e = (s2 ? b - EBLK : b) * 256 + threadIdx.x;
    if (e >= NE) return;
    atomicAdd(&cnt[ei[e]], 1);
}

// ---------------- parallel scan phase 1, both sets ----------------
__global__ void k_scan_part2(const int* __restrict__ cnt1, const int* __restrict__ cnt2,
                             int* __restrict__ part1, int* __restrict__ part2) {
    __shared__ int red[256];
    const int b = blockIdx.x;
    const bool s2 = (b >= SCAN_BLOCKS);
    const int* cnt = s2 ? cnt2 : cnt1;
    int* partials = s2 ? part2 : part1;
    const int bb = s2 ? b - SCAN_BLOCKS : b;
    const int tid = threadIdx.x;
    const int i = bb * 256 + tid;
    red[tid] = (i < NN) ? cnt[i] : 0;
    __syncthreads();
    for (int s = 128; s > 0; s >>= 1) {
        if (tid < s) red[tid] += red[tid + s];
        __syncthreads();
    }
    if (tid == 0) partials[bb] = red[0];
}

// ---------------- phase 2, both sets (2 blocks) ----------------
__global__ void k_scan_mid2(const int* __restrict__ part1, const int* __restrict__ part2,
                            int* __restrict__ offs1, int* __restrict__ offs2) {
    __shared__ int part[256];
    const bool s2 = (blockIdx.x == 1);
    const int* partials = s2 ? part2 : part1;
    int* offs = s2 ? offs2 : offs1;
    const int tid = threadIdx.x;
    const int v = (tid < SCAN_BLOCKS) ? partials[tid] : 0;
    part[tid] = v;
    __syncthreads();
    for (int off = 1; off < 256; off <<= 1) {
        int t = (tid >= off) ? part[tid - off] : 0;
        __syncthreads();
        part[tid] += t;
        __syncthreads();
    }
    if (tid < SCAN_BLOCKS) offs[tid] = part[tid] - v;
}

// ---------------- phase 3, both sets ----------------
__global__ void k_scan_fill2(const int* __restrict__ cnt1, const int* __restrict__ cnt2,
                             const int* __restrict__ offs1, const int* __restrict__ offs2,
                             int* __restrict__ rs1, int* __restrict__ rs2) {
    __shared__ int part[256];
    const int b = blockIdx.x;
    const bool s2 = (b >= SCAN_BLOCKS);
    const int* cnt = s2 ? cnt2 : cnt1;
    const int* offs = s2 ? offs2 : offs1;
    int* row_start = s2 ? rs2 : rs1;
    const int bb = s2 ? b - SCAN_BLOCKS : b;
    const int tid = threadIdx.x;
    const int i = bb * 256 + tid;
    const int v = (i < NN) ? cnt[i] : 0;
    part[tid] = v;
    __syncthreads();
    for (int off = 1; off < 256; off <<= 1) {
        int t = (tid >= off) ? part[tid - off] : 0;
        __syncthreads();
        part[tid] += t;
        __syncthreads();
    }
    const int excl = part[tid] - v + offs[bb];
    if (i < NN) row_start[i] = excl;
    if (i == NN - 1) row_start[NN] = NE;
}

// ---------------- bucket cursor init: bcur[b] = rs[b*32], both sets ----------------
__global__ void k_bcur2(const int* __restrict__ rs1, const int* __restrict__ rs2,
                        int* __restrict__ bcur1, int* __restrict__ bcur2) {
    const int i = blockIdx.x * 256 + threadIdx.x;
    if (i < NBUCK)      bcur1[i] = rs1[i * 32];
    else if (i < 2 * NBUCK) bcur2[(i - NBUCK)] = rs2[(i - NBUCK) * 32];
}

// ---------------- phase A: append edge records to 32-row buckets ----------------
// tmp rec = {((r&31)<<26)|col, half2(e0,e1), half2(e2,0), 0}
__global__ void k_bucket2(const int* __restrict__ ei1, const int* __restrict__ ei2,
                          const float* __restrict__ w1, const float* __restrict__ w2,
                          int* __restrict__ bcur1, int* __restrict__ bcur2,
                          uint4* __restrict__ tmp1, uint4* __restrict__ tmp2) {
    const int b = blockIdx.x;
    const bool s2 = (b >= EBLK);
    const int* ei = s2 ? ei2 : ei1;
    const float* ew = s2 ? w2 : w1;
    int* bcur = s2 ? bcur2 : bcur1;
    uint4* tmp = s2 ? tmp2 : tmp1;
    int e = (s2 ? b - EBLK : b) * 256 + threadIdx.x;
    if (e >= NE) return;
    const int r = ei[e];
    const int c = ei[NE + e];
    const int pos = atomicAdd(&bcur[r >> 5], 1);
    const __half2 h01 = __floats2half2_rn(ew[3 * e], ew[3 * e + 1]);
    const __half2 h2  = __floats2half2_rn(ew[3 * e + 2], 0.f);
    tmp[pos] = make_uint4((unsigned)(((r & 31) << 26) | c),
                          *(const unsigned*)&h01, *(const unsigned*)&h2, 0u);
}

// ---------------- phase B: within-bucket CSR sort (LDS cursors), both sets ----------------
__global__ void k_bsort2(const uint4* __restrict__ tmp1, const uint4* __restrict__ tmp2,
                         const int* __restrict__ rs1, const int* __restrict__ rs2,
                         uint4* __restrict__ rec1, uint4* __restrict__ rec2) {
    __shared__ int curs[32];
    const int b = blockIdx.x;
    const bool s2 = (b >= NBUCK);
    const uint4* tmp = s2 ? tmp2 : tmp1;
    const int* rs = s2 ? rs2 : rs1;
    uint4* rec = s2 ? rec2 : rec1;
    const int bb = s2 ? b - NBUCK : b;
    const int R0 = bb * 32;
    const int tid = threadIdx.x;
    if (tid < 32) curs[tid] = rs[R0 + tid];
    __syncthreads();
    const int pbeg = rs[R0], pend = rs[R0 + 32];
    for (int p = pbeg + tid; p < pend; p += 256) {
        uint4 t = tmp[p];
        const int lr = (int)(t.x >> 26);
        const int pos = atomicAdd(&curs[lr], 1);
        t.x = (unsigned)(((lr & 7) << 28) | (t.x & 0x03FFFFFFu));
        rec[pos] = t;
    }
}

// ---------------- one-time: Wt[c][k] = f16(W_big[k][c]) (CGConv weights) ----------------
__global__ void k_wt16(const float* __restrict__ lfw, const float* __restrict__ lsw,
                       _Float16* __restrict__ Wt) {
    const int k = blockIdx.x;       // 0..63
    const int c = threadIdx.x;      // 0..255
    float v;
    if (c < 64)       v = lfw[k * 64 + c];
    else if (c < 128) v = lsw[k * 64 + (c - 64)];
    else if (c < 192) v = lfw[(64 + k) * 64 + (c - 128)];
    else              v = lsw[(64 + k) * 64 + (c - 192)];
    Wt[c * 64 + k] = (_Float16)v;
}

// ---------------- one-time: WtG[c][k] f16 — GRU weights ----------------
__global__ void k_wtg16(const float* __restrict__ wih, const float* __restrict__ whh,
                        _Float16* __restrict__ WtG) {
    const int i = blockIdx.x * 256 + threadIdx.x;   // 0..24575
    const int c = i >> 6, k = i & 63;
    const float v = (c < 192) ? wih[k * 192 + c] : whh[k * 192 + (c - 192)];
    WtG[c * 64 + k] = (_Float16)v;
}

// ---------------- MFMA node projection ----------------
__launch_bounds__(256, 4)
__global__ void k_proj_mfma(const float* __restrict__ x,
                            const _Float16* __restrict__ Wt,
                            const float* __restrict__ bfp, const float* __restrict__ bsp,
                            float* __restrict__ Pi, __half2* __restrict__ Pj16) {
    __shared__ _Float16 xs16[32][72];
    const int tid = threadIdx.x;
    const int n0 = blockIdx.x * 32;
    {
        const int n = tid >> 3, k0 = (tid & 7) * 8;
        const float4 a = *(const float4*)&x[(size_t)(n0 + n) * 64 + k0];
        const float4 b = *(const float4*)&x[(size_t)(n0 + n) * 64 + k0 + 4];
        f16x8 v;
        v[0] = (_Float16)a.x; v[1] = (_Float16)a.y; v[2] = (_Float16)a.z; v[3] = (_Float16)a.w;
        v[4] = (_Float16)b.x; v[5] = (_Float16)b.y; v[6] = (_Float16)b.z; v[7] = (_Float16)b.w;
        *(f16x8*)&xs16[n][k0] = v;
    }
    __syncthreads();
    const int l  = tid & 63;
    const int w  = tid >> 6;
    const int lr = l & 15;
    const int kb = l >> 4;
    const int nt = w & 1;
    const f16x8 A0 = *(const f16x8*)&xs16[nt * 16 + lr][kb * 8];
    const f16x8 A1 = *(const f16x8*)&xs16[nt * 16 + lr][32 + kb * 8];
    const int orow = n0 + nt * 16 + kb * 4;

    if (w < 2) {
        for (int ct = 0; ct < 8; ++ct) {
            const int col = ct * 16 + lr;
            const f16x8 B0 = *(const f16x8*)&Wt[col * 64 + kb * 8];
            const f16x8 B1 = *(const f16x8*)&Wt[col * 64 + 32 + kb * 8];
            f32x4 acc = {0.f, 0.f, 0.f, 0.f};
            acc = __builtin_amdgcn_mfma_f32_16x16x32_f16(A0, B0, acc, 0, 0, 0);
            acc = __builtin_amdgcn_mfma_f32_16x16x32_f16(A1, B1, acc, 0, 0, 0);
            const float bias = (col < 64) ? bfp[col] : bsp[col - 64];
            #pragma unroll
            for (int r = 0; r < 4; ++r)
                Pi[(size_t)(orow + r) * 128 + col] = acc[r] + bias;
        }
    } else {
        for (int pt = 0; pt < 4; ++pt) {
            const int colF = 128 + pt * 16 + lr;
            const int colS = 192 + pt * 16 + lr;
            const f16x8 BF0 = *(const f16x8*)&Wt[colF * 64 + kb * 8];
            const f16x8 BF1 = *(const f16x8*)&Wt[colF * 64 + 32 + kb * 8];
            const f16x8 BS0 = *(const f16x8*)&Wt[colS * 64 + kb * 8];
            const f16x8 BS1 = *(const f16x8*)&Wt[colS * 64 + 32 + kb * 8];
            f32x4 aF = {0.f, 0.f, 0.f, 0.f}, aS = {0.f, 0.f, 0.f, 0.f};
            aF = __builtin_amdgcn_mfma_f32_16x16x32_f16(A0, BF0, aF, 0, 0, 0);
            aF = __builtin_amdgcn_mfma_f32_16x16x32_f16(A1, BF1, aF, 0, 0, 0);
            aS = __builtin_amdgcn_mfma_f32_16x16x32_f16(A0, BS0, aS, 0, 0, 0);
            aS = __builtin_amdgcn_mfma_f32_16x16x32_f16(A1, BS1, aS, 0, 0, 0);
            const int cj = pt * 16 + lr;
            #pragma unroll
            for (int r = 0; r < 4; ++r)
                Pj16[(size_t)(orow + r) * 64 + cj] = __floats2half2_rn((float)aF[r], (float)aS[r]);
        }
    }
}

// ---------------- edge-parallel row-range conv: 16B record, 32-bit offsets, fast rcp ----------------
__launch_bounds__(256, 8)
__global__ void k_edge_range(const __half2* __restrict__ Pj,
                             const float* __restrict__ Pi,
                             const uint4* __restrict__ rec,
                             const float* __restrict__ wfe, const float* __restrict__ wse,
                             const int* __restrict__ rs,
                             const float* __restrict__ xin, float* __restrict__ out) {
    __shared__ __align__(8) __half2 piH[8][64];     // (pf,ps), 2 KB
    __shared__ __align__(16) float accS[8][8][64];  // 16 KB
    __shared__ int rsS[9];
    const int tid = threadIdx.x;
    const int hw = tid >> 5;
    const int hb = hw & 1;
    const int wv = tid >> 6;
    const int c2 = (tid & 31) * 2;
    const int r0 = blockIdx.x * 8;
    for (int i = tid; i < 512; i += 256) {
        const int row = i >> 6, ch = i & 63;
        piH[row][ch] = __floats2half2_rn(Pi[(size_t)(r0 + row) * 128 + ch],
                                         Pi[(size_t)(r0 + row) * 128 + 64 + ch]);
    }
    for (int i = tid; i < 4096; i += 256)
        ((float*)accS)[i] = 0.f;
    if (tid < 9) rsS[tid] = rs[r0 + tid];
    __syncthreads();
    const float wf0a = wfe[c2],       wf0b = wfe[c2 + 1];
    const float wf1a = wfe[64 + c2],  wf1b = wfe[64 + c2 + 1];
    const float wf2a = wfe[128 + c2], wf2b = wfe[128 + c2 + 1];
    const float ws0a = wse[c2],       ws0b = wse[c2 + 1];
    const float ws1a = wse[64 + c2],  ws1b = wse[64 + c2 + 1];
    const float ws2a = wse[128 + c2], ws2b = wse[128 + c2 + 1];
    const int pbeg = rsS[0], pend = rsS[8];

#define EDGE_BODY(P)                                                              \
    {                                                                             \
        const uint4 rv = rec[P];                                                  \
        const float2 e01 = __half22float2(*(const __half2*)&rv.y);                \
        const float2 e2x = __half22float2(*(const __half2*)&rv.z);                \
        const int row = rv.x >> 28;                                               \
        const int joff = (int)((rv.x & 0x0FFFFFFFu) << 6) | c2;                   \
        const uint2 Jraw = *(const uint2*)(Pj + joff);                            \
        const float2 Ja = __half22float2(*(const __half2*)&Jraw.x);               \
        const float2 Jb = __half22float2(*(const __half2*)&Jraw.y);               \
        const uint2 PH = *(const uint2*)&piH[row][c2];                            \
        const float2 Pa = __half22float2(*(const __half2*)&PH.x);                 \
        const float2 Pb = __half22float2(*(const __half2*)&PH.y);                 \
        const float afa = Pa.x + Ja.x + e01.x * wf0a + e01.y * wf1a + e2x.x * wf2a; \
        const float asa = Pa.y + Ja.y + e01.x * ws0a + e01.y * ws1a + e2x.x * ws2a; \
        const float afb = Pb.x + Jb.x + e01.x * wf0b + e01.y * wf1b + e2x.x * wf2b; \
        const float asb = Pb.y + Jb.y + e01.x * ws0b + e01.y * ws1b + e2x.x * ws2b; \
        const float sga = __builtin_amdgcn_rcpf(1.f + __expf(-afa));              \
        const float spa = (asa > 20.f) ? asa : __logf(1.f + __expf(asa));         \
        const float sgb = __builtin_amdgcn_rcpf(1.f + __expf(-afb));              \
        const float spb = (asb > 20.f) ? asb : __logf(1.f + __expf(asb));         \
        float2 acc = *(const float2*)&accS[hw][row][c2];                          \
        acc.x = fmaf(sga, spa, acc.x);                                            \
        acc.y = fmaf(sgb, spb, acc.y);                                            \
        *(float2*)&accS[hw][row][c2] = acc;                                       \
    }

    int p0 = pbeg + 2 * wv;
    #pragma unroll 4
    for (; p0 + 2 <= pend; p0 += 8) {
        const int p = p0 + hb;
        EDGE_BODY(p)
    }
    {
        const int p = p0 + hb;
        if (p < pend) EDGE_BODY(p)
    }
#undef EDGE_BODY

    __syncthreads();
    for (int i = tid; i < 512; i += 256) {
        const int row = i >> 6, ch = i & 63;
        float s = 0.f;
        #pragma unroll
        for (int a = 0; a < 8; ++a) s += accS[a][row][ch];
        const int deg = rsS[row + 1] - rsS[row];
        const size_t o = (size_t)(r0 + row) * 64 + ch;
        out[o] = fmaxf(fmaf(s, 1.f / (float)max(deg, 1), xin[o]), 0.f);
    }
}

// ---------------- MFMA GRU: h = GRU(m, h) ----------------
__global__ void k_gru_mfma(const float* __restrict__ m, float* __restrict__ h,
                           const _Float16* __restrict__ WtG,
                           const float* __restrict__ bih, const float* __restrict__ bhh) {
    __shared__ _Float16 ms16[32][72];
    __shared__ _Float16 hs16[32][72];
    __shared__ __align__(16) float hs32[32][64];
    const int tid = threadIdx.x;
    const int n0 = blockIdx.x * 32;
    {
        const int n = tid >> 3, k0 = (tid & 7) * 8;
        const float4 ma = *(const float4*)&m[(size_t)(n0 + n) * 64 + k0];
        const float4 mb = *(const float4*)&m[(size_t)(n0 + n) * 64 + k0 + 4];
        const float4 ha = *(const float4*)&h[(size_t)(n0 + n) * 64 + k0];
        const float4 hb = *(const float4*)&h[(size_t)(n0 + n) * 64 + k0 + 4];
        f16x8 mv, hv;
        mv[0] = (_Float16)ma.x; mv[1] = (_Float16)ma.y; mv[2] = (_Float16)ma.z; mv[3] = (_Float16)ma.w;
        mv[4] = (_Float16)mb.x; mv[5] = (_Float16)mb.y; mv[6] = (_Float16)mb.z; mv[7] = (_Float16)mb.w;
        hv[0] = (_Float16)ha.x; hv[1] = (_Float16)ha.y; hv[2] = (_Float16)ha.z; hv[3] = (_Float16)ha.w;
        hv[4] = (_Float16)hb.x; hv[5] = (_Float16)hb.y; hv[6] = (_Float16)hb.z; hv[7] = (_Float16)hb.w;
        *(f16x8*)&ms16[n][k0] = mv;
        *(f16x8*)&hs16[n][k0] = hv;
        *(float4*)&hs32[n][k0] = ha;
        *(float4*)&hs32[n][k0 + 4] = hb;
    }
    __syncthreads();
    const int l  = tid & 63;
    const int w  = tid >> 6;
    const int lr = l & 15;
    const int kb = l >> 4;
    const int nt = w & 1;
    const int cg = w >> 1;
    const f16x8 A0 = *(const f16x8*)&ms16[nt * 16 + lr][kb * 8];
    const f16x8 A1 = *(const f16x8*)&ms16[nt * 16 + lr][32 + kb * 8];
    const f16x8 H0 = *(const f16x8*)&hs16[nt * 16 + lr][kb * 8];
    const f16x8 H1 = *(const f16x8*)&hs16[nt * 16 + lr][32 + kb * 8];
    const int orow = n0 + nt * 16 + kb * 4;
    const int lrow = nt * 16 + kb * 4;

    #pragma unroll
    for (int t = 0; t < 2; ++t) {
        const int ct = cg + t * 2;
        const int c = ct * 16 + lr;
        const f16x8 BiR0 = *(const f16x8*)&WtG[(c)       * 64 + kb * 8];
        const f16x8 BiR1 = *(const f16x8*)&WtG[(c)       * 64 + 32 + kb * 8];
        const f16x8 BiZ0 = *(const f16x8*)&WtG[(64 + c)  * 64 + kb * 8];
        const f16x8 BiZ1 = *(const f16x8*)&WtG[(64 + c)  * 64 + 32 + kb * 8];
        const f16x8 BiN0 = *(const f16x8*)&WtG[(128 + c) * 64 + kb * 8];
        const f16x8 BiN1 = *(const f16x8*)&WtG[(128 + c) * 64 + 32 + kb * 8];
        const f16x8 BhR0 = *(const f16x8*)&WtG[(192 + c) * 64 + kb * 8];
        const f16x8 BhR1 = *(const f16x8*)&WtG[(192 + c) * 64 + 32 + kb * 8];
        const f16x8 BhZ0 = *(const f16x8*)&WtG[(256 + c) * 64 + kb * 8];
        const f16x8 BhZ1 = *(const f16x8*)&WtG[(256 + c) * 64 + 32 + kb * 8];
        const f16x8 BhN0 = *(const f16x8*)&WtG[(320 + c) * 64 + kb * 8];
        const f16x8 BhN1 = *(const f16x8*)&WtG[(320 + c) * 64 + 32 + kb * 8];
        f32x4 aIR = {0,0,0,0}, aIZ = {0,0,0,0}, aIN = {0,0,0,0};
        f32x4 aHR = {0,0,0,0}, aHZ = {0,0,0,0}, aHN = {0,0,0,0};
        aIR = __builtin_amdgcn_mfma_f32_16x16x32_f16(A0, BiR0, aIR, 0, 0, 0);
        aIR = __builtin_amdgcn_mfma_f32_16x16x32_f16(A1, BiR1, aIR, 0, 0, 0);
        aIZ = __builtin_amdgcn_mfma_f32_16x16x32_f16(A0, BiZ0, aIZ, 0, 0, 0);
        aIZ = __builtin_amdgcn_mfma_f32_16x16x32_f16(A1, BiZ1, aIZ, 0, 0, 0);
        aIN = __builtin_amdgcn_mfma_f32_16x16x32_f16(A0, BiN0, aIN, 0, 0, 0);
        aIN = __builtin_amdgcn_mfma_f32_16x16x32_f16(A1, BiN1, aIN, 0, 0, 0);
        aHR = __builtin_amdgcn_mfma_f32_16x16x32_f16(H0, BhR0, aHR, 0, 0, 0);
        aHR = __builtin_amdgcn_mfma_f32_16x16x32_f16(H1, BhR1, aHR, 0, 0, 0);
        aHZ = __builtin_amdgcn_mfma_f32_16x16x32_f16(H0, BhZ0, aHZ, 0, 0, 0);
        aHZ = __builtin_amdgcn_mfma_f32_16x16x32_f16(H1, BhZ1, aHZ, 0, 0, 0);
        aHN = __builtin_amdgcn_mfma_f32_16x16x32_f16(H0, BhN0, aHN, 0, 0, 0);
        aHN = __builtin_amdgcn_mfma_f32_16x16x32_f16(H1, BhN1, aHN, 0, 0, 0);
        const float bir = bih[c], biz = bih[64 + c], bin = bih[128 + c];
        const float bhr = bhh[c], bhz = bhh[64 + c], bhn = bhh[128 + c];
        #pragma unroll
        for (int r = 0; r < 4; ++r) {
            const float rg = 1.f / (1.f + __expf(-(((float)aIR[r] + bir) + ((float)aHR[r] + bhr))));
            const float zg = 1.f / (1.f + __expf(-(((float)aIZ[r] + biz) + ((float)aHZ[r] + bhz))));
            const float ng = tanhf(((float)aIN[r] + bin) + rg * ((float)aHN[r] + bhn));
            h[(size_t)(orow + r) * 64 + c] = (1.f - zg) * ng + zg * hs32[lrow + r][c];
        }
    }
}

// ---------------- readout head (idx fused in) ----------------
__global__ void k_head(const float* __restrict__ h, const int* __restrict__ batch,
                       const float* __restrict__ fcsw, const float* __restrict__ fcsb,
                       const float* __restrict__ f2cw, const float* __restrict__ f2cb,
                       const float* __restrict__ f3cw, const float* __restrict__ f3cb,
                       const float* __restrict__ f2dw, const float* __restrict__ f2db,
                       const float* __restrict__ f3dw, const float* __restrict__ f3db,
                       float* __restrict__ out) {
    __shared__ float hsB[4096];
    __shared__ float waB[4096];
    __shared__ float wbB[4096];
    __shared__ float wcB[4096];
    __shared__ int sidx[64];
    const int tid = threadIdx.x;
    if (tid < 64) {
        int lo = 0, hi = NN;
        while (lo < hi) {
            int mid = (lo + hi) >> 1;
            if (batch[mid] < tid) lo = mid + 1; else hi = mid;
        }
        sidx[tid] = lo;
    }
    __syncthreads();
    for (int i = tid; i < 4096; i += 256) {
        int g = i >> 6, k = i & 63;
        hsB[i] = h[(size_t)sidx[g] * 64 + k];
        waB[i] = fcsw[i];
        wbB[i] = f2cw[i];
        wcB[i] = f2dw[i];
    }
    __syncthreads();
    float v[16];
    #pragma unroll
    for (int j = 0; j < 16; ++j) {
        const int i = j * 256 + tid, g = i >> 6, c = i & 63;
        float a = fcsb[c];
        for (int k = 0; k < 64; ++k) a = fmaf(hsB[g * 64 + k], waB[k * 64 + c], a);
        v[j] = fmaxf(a, 0.f);
    }
    __syncthreads();
    #pragma unroll
    for (int j = 0; j < 16; ++j) hsB[j * 256 + tid] = v[j];
    __syncthreads();
    float vc[16], vd[16];
    #pragma unroll
    for (int j = 0; j < 16; ++j) {
        const int i = j * 256 + tid, g = i >> 6, c = i & 63;
        float a1 = f2cb[c], a2 = f2db[c];
        for (int k = 0; k < 64; ++k) {
            const float xv = hsB[g * 64 + k];
            a1 = fmaf(xv, wbB[k * 64 + c], a1);
            a2 = fmaf(xv, wcB[k * 64 + c], a2);
        }
        vc[j] = fmaxf(a1, 0.f);
        vd[j] = fmaxf(a2, 0.f);
    }
    __syncthreads();
    #pragma unroll
    for (int j = 0; j < 16; ++j) {
        waB[j * 256 + tid] = vc[j];
        wbB[j * 256 + tid] = vd[j];
    }
    if (tid < 128) wcB[tid] = f3cw[tid];
    else           wcB[tid] = f3dw[tid - 128];
    __syncthreads();
    if (tid < 128) {
        int g = tid >> 1, j = tid & 1;
        float a = f3cb[j];
        for (int k = 0; k < 64; ++k) a = fmaf(waB[g * 64 + k], wcB[k * 2 + j], a);
        out[g * 2 + j] = 1.f / (1.f + expf(-a));
    } else {
        int t = tid - 128, g = t >> 1, j = t & 1;
        float a = f3db[j];
        for (int k = 0; k < 64; ++k) a = fmaf(wbB[g * 64 + k], wcB[128 + k * 2 + j], a);
        out[128 + g * 2 + j] = a;
    }
}

// ---------------- host launcher ----------------
extern "C" void kernel_launch(void* const* d_in, const int* in_sizes, int n_in,
                              void* d_out, int out_size, void* d_ws, size_t ws_size,
                              hipStream_t stream) {
    (void)in_sizes; (void)n_in; (void)out_size; (void)ws_size;
    const float* x    = (const float*)d_in[0];
    const int* ei1    = (const int*)d_in[1];
    const int* ei2    = (const int*)d_in[2];
    const float* w1   = (const float*)d_in[3];
    const float* w2   = (const float*)d_in[4];
    const int* batch  = (const int*)d_in[5];
    const float* fc1w = (const float*)d_in[6];
    const float* fc1b = (const float*)d_in[7];
    const float* lfw  = (const float*)d_in[8];
    const float* lfb  = (const float*)d_in[9];
    const float* lsw  = (const float*)d_in[10];
    const float* lsb  = (const float*)d_in[11];
    const float* wih  = (const float*)d_in[12];
    const float* bih  = (const float*)d_in[13];
    const float* whh  = (const float*)d_in[14];
    const float* bhh  = (const float*)d_in[15];
    const float* fcsw = (const float*)d_in[16];
    const float* fcsb = (const float*)d_in[17];
    const float* f2cw = (const float*)d_in[18];
    const float* f2cb = (const float*)d_in[19];
    const float* f3cw = (const float*)d_in[20];
    const float* f3cb = (const float*)d_in[21];
    const float* f2dw = (const float*)d_in[22];
    const float* f2db = (const float*)d_in[23];
    const float* f3dw = (const float*)d_in[24];
    const float* f3db = (const float*)d_in[25];

    char* ws = (char*)d_ws;
    size_t off = 0;
    auto alloc = [&](size_t bytes) { char* p = ws + off; off += (bytes + 255) & ~size_t(255); return p; };
    float*   Pi    = (float*)alloc(size_t(NN) * 128 * 4);      // 20.5 MB
    __half2* Pj16  = (__half2*)alloc(size_t(NN) * 64 * 4);     // 10.2 MB
    float*   hbuf  = (float*)alloc(size_t(NN) * CD * 4);
    float*   mbuf  = (float*)alloc(size_t(NN) * CD * 4);
    _Float16* W16  = (_Float16*)alloc(256 * 64 * 2);           // 32 KB
    _Float16* WG16 = (_Float16*)alloc(384 * 64 * 2);           // 48 KB
    int*   cnt1  = (int*)alloc(size_t(NN) * 4);
    int*   cnt2  = (int*)alloc(size_t(NN) * 4);
    int*   rs1   = (int*)alloc(size_t(NN + 1) * 4);
    int*   rs2   = (int*)alloc(size_t(NN + 1) * 4);
    int*   bcur1 = (int*)alloc(size_t(NBUCK) * 4);
    int*   bcur2 = (int*)alloc(size_t(NBUCK) * 4);
    uint4* tmp1  = (uint4*)alloc(size_t(NE) * 16);             // 6.4 MB
    uint4* tmp2  = (uint4*)alloc(size_t(NE) * 16);
    uint4* rec1  = (uint4*)alloc(size_t(NE) * 16);
    uint4* rec2  = (uint4*)alloc(size_t(NE) * 16);
    int*   part1 = (int*)alloc(256 * 4);
    int*   part2 = (int*)alloc(256 * 4);
    int*   offs1 = (int*)alloc(256 * 4);
    int*   offs2 = (int*)alloc(256 * 4);

    const int NB_NC = (NN * CD + 255) / 256;
    const int EDGE_BLOCKS = NN / 8;     // 5000
    const int PROJ_BLOCKS = NN / 32;    // 1250
    const int GRU_BLOCKS  = NN / 32;    // 1250

    const float* lfe = lfw + 128 * 64;
    const float* lse = lsw + 128 * 64;

    // CSR build via two-phase bucket sort + one-time f16 weight transposes
    hipMemsetAsync(cnt1, 0, size_t(NN) * 4 * 2 + 256, stream);
    k_count2<<<2 * EBLK, 256, 0, stream>>>(ei1, ei2, cnt1, cnt2);
    k_scan_part2<<<2 * SCAN_BLOCKS, 256, 0, stream>>>(cnt1, cnt2, part1, part2);
    k_scan_mid2<<<2, 256, 0, stream>>>(part1, part2, offs1, offs2);
    k_scan_fill2<<<2 * SCAN_BLOCKS, 256, 0, stream>>>(cnt1, cnt2, offs1, offs2, rs1, rs2);
    k_bcur2<<<(2 * NBUCK + 255) / 256, 256, 0, stream>>>(rs1, rs2, bcur1, bcur2);
    k_bucket2<<<2 * EBLK, 256, 0, stream>>>(ei1, ei2, w1, w2, bcur1, bcur2, tmp1, tmp2);
    k_bsort2<<<2 * NBUCK, 256, 0, stream>>>(tmp1, tmp2, rs1, rs2, rec1, rec2);
    k_wt16<<<64, 256, 0, stream>>>(lfw, lsw, W16);
    k_wtg16<<<96, 256, 0, stream>>>(wih, whh, WG16);

    k_fc1<<<NB_NC, 256, 0, stream>>>(x, fc1w, fc1b, hbuf);

    for (int it = 0; it < 3; ++it) {
        k_proj_mfma<<<PROJ_BLOCKS, 256, 0, stream>>>(hbuf, W16, lfb, lsb, Pi, Pj16);
        k_edge_range<<<EDGE_BLOCKS, 256, 0, stream>>>(Pj16, Pi, rec2, lfe, lse, rs2, hbuf, mbuf);
        k_proj_mfma<<<PROJ_BLOCKS, 256, 0, stream>>>(mbuf, W16, lfb, lsb, Pi, Pj16);
        k_edge_range<<<EDGE_BLOCKS, 256, 0, stream>>>(Pj16, Pi, rec1, lfe, lse, rs1, mbuf, mbuf);
        k_gru_mfma<<<GRU_BLOCKS, 256, 0, stream>>>(mbuf, hbuf, WG16, bih, bhh);
    }

    k_head<<<1, 256, 0, stream>>>(hbuf, batch, fcsw, fcsb, f2cw, f2cb, f3cw, f3cb,
                                  f2dw, f2db, f3dw, f3db, (float*)d_out);
}

// Round 25
// 534.565 us; speedup vs baseline: 1.1713x; 1.1713x over previous
//
#include <hip/hip_runtime.h>
#include <hip/hip_bf16.h>
#include <hip/hip_fp16.h>
#include <math.h>

constexpr int NE = 400000;
constexpr int NN = 40000;
constexpr int CD = 64;
constexpr int NGRAPH = 64;
constexpr int SCAN_BLOCKS = (NN + 255) / 256;   // 157
constexpr int EBLK = (NE + 255) / 256;          // 1563

typedef _Float16 f16x8 __attribute__((ext_vector_type(8)));
typedef float f32x4 __attribute__((ext_vector_type(4)));

// ---------------- fc1: x0 = relu(x @ fc1_w + b) ----------------
__global__ void k_fc1(const float* __restrict__ x,
                      const float* __restrict__ w,
                      const float* __restrict__ b,
                      float* __restrict__ out) {
    int i = blockIdx.x * 256 + threadIdx.x;
    if (i >= NN * CD) return;
    int n = i >> 6, c = i & 63;
    float acc = b[c];
    #pragma unroll
    for (int k = 0; k < 9; ++k)
        acc = fmaf(x[n * 9 + k], w[k * 64 + c], acc);
    out[i] = fmaxf(acc, 0.f);
}

// ---------------- edge counts, both sets ----------------
__global__ void k_count2(const int* __restrict__ ei1, const int* __restrict__ ei2,
                         int* __restrict__ cnt1, int* __restrict__ cnt2) {
    const int b = blockIdx.x;
    const bool s2 = (b >= EBLK);
    const int* ei = s2 ? ei2 : ei1;
    int* cnt = s2 ? cnt2 : cnt1;
    int e = (s2 ? b - EBLK : b) * 256 + threadIdx.x;
    if (e >= NE) return;
    atomicAdd(&cnt[ei[e]], 1);
}

// ---------------- parallel scan phase 1, both sets ----------------
__global__ void k_scan_part2(const int* __restrict__ cnt1, const int* __restrict__ cnt2,
                             int* __restrict__ part1, int* __restrict__ part2) {
    __shared__ int red[256];
    const int b = blockIdx.x;
    const bool s2 = (b >= SCAN_BLOCKS);
    const int* cnt = s2 ? cnt2 : cnt1;
    int* partials = s2 ? part2 : part1;
    const int bb = s2 ? b - SCAN_BLOCKS : b;
    const int tid = threadIdx.x;
    const int i = bb * 256 + tid;
    red[tid] = (i < NN) ? cnt[i] : 0;
    __syncthreads();
    for (int s = 128; s > 0; s >>= 1) {
        if (tid < s) red[tid] += red[tid + s];
        __syncthreads();
    }
    if (tid == 0) partials[bb] = red[0];
}

// ---------------- phase 2, both sets (2 blocks) ----------------
__global__ void k_scan_mid2(const int* __restrict__ part1, const int* __restrict__ part2,
                            int* __restrict__ offs1, int* __restrict__ offs2) {
    __shared__ int part[256];
    const bool s2 = (blockIdx.x == 1);
    const int* partials = s2 ? part2 : part1;
    int* offs = s2 ? offs2 : offs1;
    const int tid = threadIdx.x;
    const int v = (tid < SCAN_BLOCKS) ? partials[tid] : 0;
    part[tid] = v;
    __syncthreads();
    for (int off = 1; off < 256; off <<= 1) {
        int t = (tid >= off) ? part[tid - off] : 0;
        __syncthreads();
        part[tid] += t;
        __syncthreads();
    }
    if (tid < SCAN_BLOCKS) offs[tid] = part[tid] - v;
}

// ---------------- phase 3, both sets ----------------
__global__ void k_scan_fill2(const int* __restrict__ cnt1, const int* __restrict__ cnt2,
                             const int* __restrict__ offs1, const int* __restrict__ offs2,
                             int* __restrict__ rs1, int* __restrict__ rs2,
                             int* __restrict__ cur1, int* __restrict__ cur2) {
    __shared__ int part[256];
    const int b = blockIdx.x;
    const bool s2 = (b >= SCAN_BLOCKS);
    const int* cnt = s2 ? cnt2 : cnt1;
    const int* offs = s2 ? offs2 : offs1;
    int* row_start = s2 ? rs2 : rs1;
    int* cursor = s2 ? cur2 : cur1;
    const int bb = s2 ? b - SCAN_BLOCKS : b;
    const int tid = threadIdx.x;
    const int i = bb * 256 + tid;
    const int v = (i < NN) ? cnt[i] : 0;
    part[tid] = v;
    __syncthreads();
    for (int off = 1; off < 256; off <<= 1) {
        int t = (tid >= off) ? part[tid - off] : 0;
        __syncthreads();
        part[tid] += t;
        __syncthreads();
    }
    const int excl = part[tid] - v + offs[bb];
    if (i < NN) { row_start[i] = excl; cursor[i] = excl; }
    if (i == NN - 1) row_start[NN] = NE;
}

// ---------------- merged scatter+gather: single 16B record per edge ----------------
// rec = {((r&7)<<28)|col, half2(e0,e1), half2(e2,0), 0}
__global__ void k_scatgath2(const int* __restrict__ ei1, const int* __restrict__ ei2,
                            const float* __restrict__ w1, const float* __restrict__ w2,
                            int* __restrict__ cur1, int* __restrict__ cur2,
                            uint4* __restrict__ rec1, uint4* __restrict__ rec2) {
    const int b = blockIdx.x;
    const bool s2 = (b >= EBLK);
    const int* ei = s2 ? ei2 : ei1;
    const float* ew = s2 ? w2 : w1;
    int* cursor = s2 ? cur2 : cur1;
    uint4* rec = s2 ? rec2 : rec1;
    int e = (s2 ? b - EBLK : b) * 256 + threadIdx.x;
    if (e >= NE) return;
    const int r = ei[e];
    const int c = ei[NE + e];
    const int pos = atomicAdd(&cursor[r], 1);
    const __half2 h01 = __floats2half2_rn(ew[3 * e], ew[3 * e + 1]);
    const __half2 h2  = __floats2half2_rn(ew[3 * e + 2], 0.f);
    rec[pos] = make_uint4((unsigned)(((r & 7) << 28) | c),
                          *(const unsigned*)&h01, *(const unsigned*)&h2, 0u);
}

// ---------------- one-time: Wt[c][k] = f16(W_big[k][c]) (CGConv weights) ----------------
__global__ void k_wt16(const float* __restrict__ lfw, const float* __restrict__ lsw,
                       _Float16* __restrict__ Wt) {
    const int k = blockIdx.x;       // 0..63
    const int c = threadIdx.x;      // 0..255
    float v;
    if (c < 64)       v = lfw[k * 64 + c];
    else if (c < 128) v = lsw[k * 64 + (c - 64)];
    else if (c < 192) v = lfw[(64 + k) * 64 + (c - 128)];
    else              v = lsw[(64 + k) * 64 + (c - 192)];
    Wt[c * 64 + k] = (_Float16)v;
}

// ---------------- one-time: WtG[c][k] f16 — GRU weights ----------------
__global__ void k_wtg16(const float* __restrict__ wih, const float* __restrict__ whh,
                        _Float16* __restrict__ WtG) {
    const int i = blockIdx.x * 256 + threadIdx.x;   // 0..24575
    const int c = i >> 6, k = i & 63;
    const float v = (c < 192) ? wih[k * 192 + c] : whh[k * 192 + (c - 192)];
    WtG[c * 64 + k] = (_Float16)v;
}

// ---------------- MFMA node projection ----------------
__launch_bounds__(256, 4)
__global__ void k_proj_mfma(const float* __restrict__ x,
                            const _Float16* __restrict__ Wt,
                            const float* __restrict__ bfp, const float* __restrict__ bsp,
                            float* __restrict__ Pi, __half2* __restrict__ Pj16) {
    __shared__ _Float16 xs16[32][72];
    const int tid = threadIdx.x;
    const int n0 = blockIdx.x * 32;
    {
        const int n = tid >> 3, k0 = (tid & 7) * 8;
        const float4 a = *(const float4*)&x[(size_t)(n0 + n) * 64 + k0];
        const float4 b = *(const float4*)&x[(size_t)(n0 + n) * 64 + k0 + 4];
        f16x8 v;
        v[0] = (_Float16)a.x; v[1] = (_Float16)a.y; v[2] = (_Float16)a.z; v[3] = (_Float16)a.w;
        v[4] = (_Float16)b.x; v[5] = (_Float16)b.y; v[6] = (_Float16)b.z; v[7] = (_Float16)b.w;
        *(f16x8*)&xs16[n][k0] = v;
    }
    __syncthreads();
    const int l  = tid & 63;
    const int w  = tid >> 6;
    const int lr = l & 15;
    const int kb = l >> 4;
    const int nt = w & 1;
    const f16x8 A0 = *(const f16x8*)&xs16[nt * 16 + lr][kb * 8];
    const f16x8 A1 = *(const f16x8*)&xs16[nt * 16 + lr][32 + kb * 8];
    const int orow = n0 + nt * 16 + kb * 4;

    if (w < 2) {
        for (int ct = 0; ct < 8; ++ct) {
            const int col = ct * 16 + lr;
            const f16x8 B0 = *(const f16x8*)&Wt[col * 64 + kb * 8];
            const f16x8 B1 = *(const f16x8*)&Wt[col * 64 + 32 + kb * 8];
            f32x4 acc = {0.f, 0.f, 0.f, 0.f};
            acc = __builtin_amdgcn_mfma_f32_16x16x32_f16(A0, B0, acc, 0, 0, 0);
            acc = __builtin_amdgcn_mfma_f32_16x16x32_f16(A1, B1, acc, 0, 0, 0);
            const float bias = (col < 64) ? bfp[col] : bsp[col - 64];
            #pragma unroll
            for (int r = 0; r < 4; ++r)
                Pi[(size_t)(orow + r) * 128 + col] = acc[r] + bias;
        }
    } else {
        for (int pt = 0; pt < 4; ++pt) {
            const int colF = 128 + pt * 16 + lr;
            const int colS = 192 + pt * 16 + lr;
            const f16x8 BF0 = *(const f16x8*)&Wt[colF * 64 + kb * 8];
            const f16x8 BF1 = *(const f16x8*)&Wt[colF * 64 + 32 + kb * 8];
            const f16x8 BS0 = *(const f16x8*)&Wt[colS * 64 + kb * 8];
            const f16x8 BS1 = *(const f16x8*)&Wt[colS * 64 + 32 + kb * 8];
            f32x4 aF = {0.f, 0.f, 0.f, 0.f}, aS = {0.f, 0.f, 0.f, 0.f};
            aF = __builtin_amdgcn_mfma_f32_16x16x32_f16(A0, BF0, aF, 0, 0, 0);
            aF = __builtin_amdgcn_mfma_f32_16x16x32_f16(A1, BF1, aF, 0, 0, 0);
            aS = __builtin_amdgcn_mfma_f32_16x16x32_f16(A0, BS0, aS, 0, 0, 0);
            aS = __builtin_amdgcn_mfma_f32_16x16x32_f16(A1, BS1, aS, 0, 0, 0);
            const int cj = pt * 16 + lr;
            #pragma unroll
            for (int r = 0; r < 4; ++r)
                Pj16[(size_t)(orow + r) * 64 + cj] = __floats2half2_rn((float)aF[r], (float)aS[r]);
        }
    }
}

// ---------------- edge-parallel row-range conv: 16B record, 32-bit offsets, fast rcp ----------------
__launch_bounds__(256, 8)
__global__ void k_edge_range(const __half2* __restrict__ Pj,
                             const float* __restrict__ Pi,
                             const uint4* __restrict__ rec,
                             const float* __restrict__ wfe, const float* __restrict__ wse,
                             const int* __restrict__ rs,
                             const float* __restrict__ xin, float* __restrict__ out) {
    __shared__ __align__(8) __half2 piH[8][64];     // (pf,ps), 2 KB
    __shared__ __align__(16) float accS[8][8][64];  // 16 KB
    __shared__ int rsS[9];
    const int tid = threadIdx.x;
    const int hw = tid >> 5;
    const int hb = hw & 1;
    const int wv = tid >> 6;
    const int c2 = (tid & 31) * 2;
    const int r0 = blockIdx.x * 8;
    for (int i = tid; i < 512; i += 256) {
        const int row = i >> 6, ch = i & 63;
        piH[row][ch] = __floats2half2_rn(Pi[(size_t)(r0 + row) * 128 + ch],
                                         Pi[(size_t)(r0 + row) * 128 + 64 + ch]);
    }
    for (int i = tid; i < 4096; i += 256)
        ((float*)accS)[i] = 0.f;
    if (tid < 9) rsS[tid] = rs[r0 + tid];
    __syncthreads();
    const float wf0a = wfe[c2],       wf0b = wfe[c2 + 1];
    const float wf1a = wfe[64 + c2],  wf1b = wfe[64 + c2 + 1];
    const float wf2a = wfe[128 + c2], wf2b = wfe[128 + c2 + 1];
    const float ws0a = wse[c2],       ws0b = wse[c2 + 1];
    const float ws1a = wse[64 + c2],  ws1b = wse[64 + c2 + 1];
    const float ws2a = wse[128 + c2], ws2b = wse[128 + c2 + 1];
    const int pbeg = rsS[0], pend = rsS[8];

#define EDGE_BODY(P)                                                              \
    {                                                                             \
        const uint4 rv = rec[P];                                                  \
        const float2 e01 = __half22float2(*(const __half2*)&rv.y);                \
        const float2 e2x = __half22float2(*(const __half2*)&rv.z);                \
        const int row = rv.x >> 28;                                               \
        const int joff = (int)((rv.x & 0x0FFFFFFFu) << 6) | c2;                   \
        const uint2 Jraw = *(const uint2*)(Pj + joff);                            \
        const float2 Ja = __half22float2(*(const __half2*)&Jraw.x);               \
        const float2 Jb = __half22float2(*(const __half2*)&Jraw.y);               \
        const uint2 PH = *(const uint2*)&piH[row][c2];                            \
        const float2 Pa = __half22float2(*(const __half2*)&PH.x);                 \
        const float2 Pb = __half22float2(*(const __half2*)&PH.y);                 \
        const float afa = Pa.x + Ja.x + e01.x * wf0a + e01.y * wf1a + e2x.x * wf2a; \
        const float asa = Pa.y + Ja.y + e01.x * ws0a + e01.y * ws1a + e2x.x * ws2a; \
        const float afb = Pb.x + Jb.x + e01.x * wf0b + e01.y * wf1b + e2x.x * wf2b; \
        const float asb = Pb.y + Jb.y + e01.x * ws0b + e01.y * ws1b + e2x.x * ws2b; \
        const float sga = __builtin_amdgcn_rcpf(1.f + __expf(-afa));              \
        const float spa = (asa > 20.f) ? asa : __logf(1.f + __expf(asa));         \
        const float sgb = __builtin_amdgcn_rcpf(1.f + __expf(-afb));              \
        const float spb = (asb > 20.f) ? asb : __logf(1.f + __expf(asb));         \
        float2 acc = *(const float2*)&accS[hw][row][c2];                          \
        acc.x = fmaf(sga, spa, acc.x);                                            \
        acc.y = fmaf(sgb, spb, acc.y);                                            \
        *(float2*)&accS[hw][row][c2] = acc;                                       \
    }

    int p0 = pbeg + 2 * wv;
    #pragma unroll 2
    for (; p0 + 2 <= pend; p0 += 8) {
        const int p = p0 + hb;
        EDGE_BODY(p)
    }
    {
        const int p = p0 + hb;
        if (p < pend) EDGE_BODY(p)
    }
#undef EDGE_BODY

    __syncthreads();
    for (int i = tid; i < 512; i += 256) {
        const int row = i >> 6, ch = i & 63;
        float s = 0.f;
        #pragma unroll
        for (int a = 0; a < 8; ++a) s += accS[a][row][ch];
        const int deg = rsS[row + 1] - rsS[row];
        const size_t o = (size_t)(r0 + row) * 64 + ch;
        out[o] = fmaxf(fmaf(s, 1.f / (float)max(deg, 1), xin[o]), 0.f);
    }
}

// ---------------- MFMA GRU: h = GRU(m, h) ----------------
__global__ void k_gru_mfma(const float* __restrict__ m, float* __restrict__ h,
                           const _Float16* __restrict__ WtG,
                           const float* __restrict__ bih, const float* __restrict__ bhh) {
    __shared__ _Float16 ms16[32][72];
    __shared__ _Float16 hs16[32][72];
    __shared__ __align__(16) float hs32[32][64];
    const int tid = threadIdx.x;
    const int n0 = blockIdx.x * 32;
    {
        const int n = tid >> 3, k0 = (tid & 7) * 8;
        const float4 ma = *(const float4*)&m[(size_t)(n0 + n) * 64 + k0];
        const float4 mb = *(const float4*)&m[(size_t)(n0 + n) * 64 + k0 + 4];
        const float4 ha = *(const float4*)&h[(size_t)(n0 + n) * 64 + k0];
        const float4 hb = *(const float4*)&h[(size_t)(n0 + n) * 64 + k0 + 4];
        f16x8 mv, hv;
        mv[0] = (_Float16)ma.x; mv[1] = (_Float16)ma.y; mv[2] = (_Float16)ma.z; mv[3] = (_Float16)ma.w;
        mv[4] = (_Float16)mb.x; mv[5] = (_Float16)mb.y; mv[6] = (_Float16)mb.z; mv[7] = (_Float16)mb.w;
        hv[0] = (_Float16)ha.x; hv[1] = (_Float16)ha.y; hv[2] = (_Float16)ha.z; hv[3] = (_Float16)ha.w;
        hv[4] = (_Float16)hb.x; hv[5] = (_Float16)hb.y; hv[6] = (_Float16)hb.z; hv[7] = (_Float16)hb.w;
        *(f16x8*)&ms16[n][k0] = mv;
        *(f16x8*)&hs16[n][k0] = hv;
        *(float4*)&hs32[n][k0] = ha;
        *(float4*)&hs32[n][k0 + 4] = hb;
    }
    __syncthreads();
    const int l  = tid & 63;
    const int w  = tid >> 6;
    const int lr = l & 15;
    const int kb = l >> 4;
    const int nt = w & 1;
    const int cg = w >> 1;
    const f16x8 A0 = *(const f16x8*)&ms16[nt * 16 + lr][kb * 8];
    const f16x8 A1 = *(const f16x8*)&ms16[nt * 16 + lr][32 + kb * 8];
    const f16x8 H0 = *(const f16x8*)&hs16[nt * 16 + lr][kb * 8];
    const f16x8 H1 = *(const f16x8*)&hs16[nt * 16 + lr][32 + kb * 8];
    const int orow = n0 + nt * 16 + kb * 4;
    const int lrow = nt * 16 + kb * 4;

    #pragma unroll
    for (int t = 0; t < 2; ++t) {
        const int ct = cg + t * 2;
        const int c = ct * 16 + lr;
        const f16x8 BiR0 = *(const f16x8*)&WtG[(c)       * 64 + kb * 8];
        const f16x8 BiR1 = *(const f16x8*)&WtG[(c)       * 64 + 32 + kb * 8];
        const f16x8 BiZ0 = *(const f16x8*)&WtG[(64 + c)  * 64 + kb * 8];
        const f16x8 BiZ1 = *(const f16x8*)&WtG[(64 + c)  * 64 + 32 + kb * 8];
        const f16x8 BiN0 = *(const f16x8*)&WtG[(128 + c) * 64 + kb * 8];
        const f16x8 BiN1 = *(const f16x8*)&WtG[(128 + c) * 64 + 32 + kb * 8];
        const f16x8 BhR0 = *(const f16x8*)&WtG[(192 + c) * 64 + kb * 8];
        const f16x8 BhR1 = *(const f16x8*)&WtG[(192 + c) * 64 + 32 + kb * 8];
        const f16x8 BhZ0 = *(const f16x8*)&WtG[(256 + c) * 64 + kb * 8];
        const f16x8 BhZ1 = *(const f16x8*)&WtG[(256 + c) * 64 + 32 + kb * 8];
        const f16x8 BhN0 = *(const f16x8*)&WtG[(320 + c) * 64 + kb * 8];
        const f16x8 BhN1 = *(const f16x8*)&WtG[(320 + c) * 64 + 32 + kb * 8];
        f32x4 aIR = {0,0,0,0}, aIZ = {0,0,0,0}, aIN = {0,0,0,0};
        f32x4 aHR = {0,0,0,0}, aHZ = {0,0,0,0}, aHN = {0,0,0,0};
        aIR = __builtin_amdgcn_mfma_f32_16x16x32_f16(A0, BiR0, aIR, 0, 0, 0);
        aIR = __builtin_amdgcn_mfma_f32_16x16x32_f16(A1, BiR1, aIR, 0, 0, 0);
        aIZ = __builtin_amdgcn_mfma_f32_16x16x32_f16(A0, BiZ0, aIZ, 0, 0, 0);
        aIZ = __builtin_amdgcn_mfma_f32_16x16x32_f16(A1, BiZ1, aIZ, 0, 0, 0);
        aIN = __builtin_amdgcn_mfma_f32_16x16x32_f16(A0, BiN0, aIN, 0, 0, 0);
        aIN = __builtin_amdgcn_mfma_f32_16x16x32_f16(A1, BiN1, aIN, 0, 0, 0);
        aHR = __builtin_amdgcn_mfma_f32_16x16x32_f16(H0, BhR0, aHR, 0, 0, 0);
        aHR = __builtin_amdgcn_mfma_f32_16x16x32_f16(H1, BhR1, aHR, 0, 0, 0);
        aHZ = __builtin_amdgcn_mfma_f32_16x16x32_f16(H0, BhZ0, aHZ, 0, 0, 0);
        aHZ = __builtin_amdgcn_mfma_f32_16x16x32_f16(H1, BhZ1, aHZ, 0, 0, 0);
        aHN = __builtin_amdgcn_mfma_f32_16x16x32_f16(H0, BhN0, aHN, 0, 0, 0);
        aHN = __builtin_amdgcn_mfma_f32_16x16x32_f16(H1, BhN1, aHN, 0, 0, 0);
        const float bir = bih[c], biz = bih[64 + c], bin = bih[128 + c];
        const float bhr = bhh[c], bhz = bhh[64 + c], bhn = bhh[128 + c];
        #pragma unroll
        for (int r = 0; r < 4; ++r) {
            const float rg = 1.f / (1.f + __expf(-(((float)aIR[r] + bir) + ((float)aHR[r] + bhr))));
            const float zg = 1.f / (1.f + __expf(-(((float)aIZ[r] + biz) + ((float)aHZ[r] + bhz))));
            const float ng = tanhf(((float)aIN[r] + bin) + rg * ((float)aHN[r] + bhn));
            h[(size_t)(orow + r) * 64 + c] = (1.f - zg) * ng + zg * hs32[lrow + r][c];
        }
    }
}

// ---------------- readout head (idx fused in) ----------------
__global__ void k_head(const float* __restrict__ h, const int* __restrict__ batch,
                       const float* __restrict__ fcsw, const float* __restrict__ fcsb,
                       const float* __restrict__ f2cw, const float* __restrict__ f2cb,
                       const float* __restrict__ f3cw, const float* __restrict__ f3cb,
                       const float* __restrict__ f2dw, const float* __restrict__ f2db,
                       const float* __restrict__ f3dw, const float* __restrict__ f3db,
                       float* __restrict__ out) {
    __shared__ float hsB[4096];
    __shared__ float waB[4096];
    __shared__ float wbB[4096];
    __shared__ float wcB[4096];
    __shared__ int sidx[64];
    const int tid = threadIdx.x;
    if (tid < 64) {
        int lo = 0, hi = NN;
        while (lo < hi) {
            int mid = (lo + hi) >> 1;
            if (batch[mid] < tid) lo = mid + 1; else hi = mid;
        }
        sidx[tid] = lo;
    }
    __syncthreads();
    for (int i = tid; i < 4096; i += 256) {
        int g = i >> 6, k = i & 63;
        hsB[i] = h[(size_t)sidx[g] * 64 + k];
        waB[i] = fcsw[i];
        wbB[i] = f2cw[i];
        wcB[i] = f2dw[i];
    }
    __syncthreads();
    float v[16];
    #pragma unroll
    for (int j = 0; j < 16; ++j) {
        const int i = j * 256 + tid, g = i >> 6, c = i & 63;
        float a = fcsb[c];
        for (int k = 0; k < 64; ++k) a = fmaf(hsB[g * 64 + k], waB[k * 64 + c], a);
        v[j] = fmaxf(a, 0.f);
    }
    __syncthreads();
    #pragma unroll
    for (int j = 0; j < 16; ++j) hsB[j * 256 + tid] = v[j];
    __syncthreads();
    float vc[16], vd[16];
    #pragma unroll
    for (int j = 0; j < 16; ++j) {
        const int i = j * 256 + tid, g = i >> 6, c = i & 63;
        float a1 = f2cb[c], a2 = f2db[c];
        for (int k = 0; k < 64; ++k) {
            const float xv = hsB[g * 64 + k];
            a1 = fmaf(xv, wbB[k * 64 + c], a1);
            a2 = fmaf(xv, wcB[k * 64 + c], a2);
        }
        vc[j] = fmaxf(a1, 0.f);
        vd[j] = fmaxf(a2, 0.f);
    }
    __syncthreads();
    #pragma unroll
    for (int j = 0; j < 16; ++j) {
        waB[j * 256 + tid] = vc[j];
        wbB[j * 256 + tid] = vd[j];
    }
    if (tid < 128) wcB[tid] = f3cw[tid];
    else           wcB[tid] = f3dw[tid - 128];
    __syncthreads();
    if (tid < 128) {
        int g = tid >> 1, j = tid & 1;
        float a = f3cb[j];
        for (int k = 0; k < 64; ++k) a = fmaf(waB[g * 64 + k], wcB[k * 2 + j], a);
        out[g * 2 + j] = 1.f / (1.f + expf(-a));
    } else {
        int t = tid - 128, g = t >> 1, j = t & 1;
        float a = f3db[j];
        for (int k = 0; k < 64; ++k) a = fmaf(wbB[g * 64 + k], wcB[128 + k * 2 + j], a);
        out[128 + g * 2 + j] = a;
    }
}

// ---------------- host launcher ----------------
extern "C" void kernel_launch(void* const* d_in, const int* in_sizes, int n_in,
                              void* d_out, int out_size, void* d_ws, size_t ws_size,
                              hipStream_t stream) {
    (void)in_sizes; (void)n_in; (void)out_size; (void)ws_size;
    const float* x    = (const float*)d_in[0];
    const int* ei1    = (const int*)d_in[1];
    const int* ei2    = (const int*)d_in[2];
    const float* w1   = (const float*)d_in[3];
    const float* w2   = (const float*)d_in[4];
    const int* batch  = (const int*)d_in[5];
    const float* fc1w = (const float*)d_in[6];
    const float* fc1b = (const float*)d_in[7];
    const float* lfw  = (const float*)d_in[8];
    const float* lfb  = (const float*)d_in[9];
    const float* lsw  = (const float*)d_in[10];
    const float* lsb  = (const float*)d_in[11];
    const float* wih  = (const float*)d_in[12];
    const float* bih  = (const float*)d_in[13];
    const float* whh  = (const float*)d_in[14];
    const float* bhh  = (const float*)d_in[15];
    const float* fcsw = (const float*)d_in[16];
    const float* fcsb = (const float*)d_in[17];
    const float* f2cw = (const float*)d_in[18];
    const float* f2cb = (const float*)d_in[19];
    const float* f3cw = (const float*)d_in[20];
    const float* f3cb = (const float*)d_in[21];
    const float* f2dw = (const float*)d_in[22];
    const float* f2db = (const float*)d_in[23];
    const float* f3dw = (const float*)d_in[24];
    const float* f3db = (const float*)d_in[25];

    char* ws = (char*)d_ws;
    size_t off = 0;
    auto alloc = [&](size_t bytes) { char* p = ws + off; off += (bytes + 255) & ~size_t(255); return p; };
    float*   Pi    = (float*)alloc(size_t(NN) * 128 * 4);      // 20.5 MB
    __half2* Pj16  = (__half2*)alloc(size_t(NN) * 64 * 4);     // 10.2 MB
    float*   hbuf  = (float*)alloc(size_t(NN) * CD * 4);
    float*   mbuf  = (float*)alloc(size_t(NN) * CD * 4);
    _Float16* W16  = (_Float16*)alloc(256 * 64 * 2);           // 32 KB
    _Float16* WG16 = (_Float16*)alloc(384 * 64 * 2);           // 48 KB
    int*   cnt1  = (int*)alloc(size_t(NN) * 4);
    int*   cnt2  = (int*)alloc(size_t(NN) * 4);
    int*   rs1   = (int*)alloc(size_t(NN + 1) * 4);
    int*   rs2   = (int*)alloc(size_t(NN + 1) * 4);
    int*   cur1  = (int*)alloc(size_t(NN + 1) * 4);
    int*   cur2  = (int*)alloc(size_t(NN + 1) * 4);
    uint4* rec1  = (uint4*)alloc(size_t(NE) * 16);             // 6.4 MB
    uint4* rec2  = (uint4*)alloc(size_t(NE) * 16);
    int*   part1 = (int*)alloc(256 * 4);
    int*   part2 = (int*)alloc(256 * 4);
    int*   offs1 = (int*)alloc(256 * 4);
    int*   offs2 = (int*)alloc(256 * 4);

    const int NB_NC = (NN * CD + 255) / 256;
    const int EDGE_BLOCKS = NN / 8;     // 5000
    const int PROJ_BLOCKS = NN / 32;    // 1250
    const int GRU_BLOCKS  = NN / 32;    // 1250

    const float* lfe = lfw + 128 * 64;
    const float* lse = lsw + 128 * 64;

    // CSR build + one-time f16 weight transposes
    hipMemsetAsync(cnt1, 0, size_t(NN) * 4 * 2 + 256, stream);
    k_count2<<<2 * EBLK, 256, 0, stream>>>(ei1, ei2, cnt1, cnt2);
    k_scan_part2<<<2 * SCAN_BLOCKS, 256, 0, stream>>>(cnt1, cnt2, part1, part2);
    k_scan_mid2<<<2, 256, 0, stream>>>(part1, part2, offs1, offs2);
    k_scan_fill2<<<2 * SCAN_BLOCKS, 256, 0, stream>>>(cnt1, cnt2, offs1, offs2, rs1, rs2, cur1, cur2);
    k_scatgath2<<<2 * EBLK, 256, 0, stream>>>(ei1, ei2, w1, w2, cur1, cur2, rec1, rec2);
    k_wt16<<<64, 256, 0, stream>>>(lfw, lsw, W16);
    k_wtg16<<<96, 256, 0, stream>>>(wih, whh, WG16);

    k_fc1<<<NB_NC, 256, 0, stream>>>(x, fc1w, fc1b, hbuf);

    for (int it = 0; it < 3; ++it) {
        k_proj_mfma<<<PROJ_BLOCKS, 256, 0, stream>>>(hbuf, W16, lfb, lsb, Pi, Pj16);
        k_edge_range<<<EDGE_BLOCKS, 256, 0, stream>>>(Pj16, Pi, rec2, lfe, lse, rs2, hbuf, mbuf);
        k_proj_mfma<<<PROJ_BLOCKS, 256, 0, stream>>>(mbuf, W16, lfb, lsb, Pi, Pj16);
        k_edge_range<<<EDGE_BLOCKS, 256, 0, stream>>>(Pj16, Pi, rec1, lfe, lse, rs1, mbuf, mbuf);
        k_gru_mfma<<<GRU_BLOCKS, 256, 0, stream>>>(mbuf, hbuf, WG16, bih, bhh);
    }

    k_head<<<1, 256, 0, stream>>>(hbuf, batch, fcsw, fcsb, f2cw, f2cb, f3cw, f3cb,
                                  f2dw, f2db, f3dw, f3db, (float*)d_out);
}